// Round 19
// baseline (262.441 us; speedup 1.0000x reference)
//
#include <hip/hip_runtime.h>
#include <math.h>

// Physics_Attention: B=1, N=65536, DIM=256, H=8, D=64, G=64
#define NPTS  65536
#define DIMX  256
#define NH    8
#define HDIM  512   // H*D

typedef __attribute__((ext_vector_type(4))) float f32x4;
typedef __attribute__((ext_vector_type(8))) short short8;
typedef __attribute__((ext_vector_type(8))) unsigned short ushort8;
typedef __attribute__((ext_vector_type(4))) unsigned short us4;

__device__ __forceinline__ ushort f2bf(float f) {   // RNE f32->bf16
    unsigned x = __float_as_uint(f);
    return (ushort)((x + 0x7fffu + ((x >> 16) & 1u)) >> 16);
}
__device__ __forceinline__ float bf2f(ushort u) {
    return __uint_as_float((unsigned)u << 16);
}
// Fast erf (A&S 7.1.26, abs err 1.5e-7) — no branches, HW exp/rcp
__device__ __forceinline__ float erf_fast(float x) {
    float ax = fabsf(x);
    float t  = __builtin_amdgcn_rcpf(1.0f + 0.3275911f * ax);
    float p  = fmaf(fmaf(fmaf(fmaf(1.061405429f, t, -1.453152027f), t,
                   1.421413741f), t, -0.284496736f), t, 0.254829592f) * t;
    float y  = 1.0f - p * __expf(-ax * ax);
    return copysignf(y, x);
}
__device__ __forceinline__ float gelu_fast(float x) {
    return 0.5f * x * (1.0f + erf_fast(x * 0.7071067811865476f));
}

// ---------------------------------------------------------------------------
// Stage 0: pre-convert x (65536x256), Wx (512x256), [Ws;Wt1] (128x64) to bf16.
// ---------------------------------------------------------------------------
__global__ __launch_bounds__(256)
void prep_kernel(const float* __restrict__ x, const float* __restrict__ Wx,
                 const float* __restrict__ Ws, const float* __restrict__ Wt1,
                 ushort* __restrict__ xb, ushort* __restrict__ Wxb,
                 ushort* __restrict__ wb) {
    const int t = threadIdx.x;
    const int b = blockIdx.x;
    if (b < 8192) {
        size_t idx = (size_t)b * 2048 + t * 8;
        float4 a0 = *(const float4*)&x[idx];
        float4 a1 = *(const float4*)&x[idx + 4];
        ushort8 v = { f2bf(a0.x), f2bf(a0.y), f2bf(a0.z), f2bf(a0.w),
                      f2bf(a1.x), f2bf(a1.y), f2bf(a1.z), f2bf(a1.w) };
        *(ushort8*)&xb[idx] = v;
    } else if (b < 8256) {
        int idx = (b - 8192) * 2048 + t * 8;
        float4 a0 = *(const float4*)&Wx[idx];
        float4 a1 = *(const float4*)&Wx[idx + 4];
        ushort8 v = { f2bf(a0.x), f2bf(a0.y), f2bf(a0.z), f2bf(a0.w),
                      f2bf(a1.x), f2bf(a1.y), f2bf(a1.z), f2bf(a1.w) };
        *(ushort8*)&Wxb[idx] = v;
    } else {
        int idx = (b - 8256) * 2048 + t * 8;   // 0..8191
        int row = idx >> 6, col = idx & 63;
        const float* src = (row < 64) ? &Ws[row * 64 + col]
                                      : &Wt1[(row - 64) * 64 + col];
        float4 a0 = *(const float4*)src;
        float4 a1 = *(const float4*)(src + 4);
        ushort8 v = { f2bf(a0.x), f2bf(a0.y), f2bf(a0.z), f2bf(a0.w),
                      f2bf(a1.x), f2bf(a1.y), f2bf(a1.z), f2bf(a1.w) };
        *(ushort8*)&wb[idx] = v;
    }
}

// ---------------------------------------------------------------------------
// Stage 1+2 FUSED (round-12 structure; bf16 xb input).
// __launch_bounds__(256,3): registers (128 VGPR + 64 AGPR ~ 192/lane) capped
// xmid_lgt1 at 2 waves/SIMD; request 3 (needs total <=170) to raise occupancy
// on this latency-bound kernel. Revert if the allocator spills to scratch.
// ---------------------------------------------------------------------------
__global__ __launch_bounds__(256, 3)
void xmid_lgt1_kernel(const ushort* __restrict__ A, const ushort* __restrict__ B,
                      const float* __restrict__ bias,
                      const ushort* __restrict__ wb,
                      const float* __restrict__ bs,  const float* __restrict__ bt1,
                      const float* __restrict__ Wt2, const float* __restrict__ bt2,
                      const float* __restrict__ biasp,
                      const float* __restrict__ u,
                      ushort* __restrict__ xmb, ushort* __restrict__ swb) {
    __shared__ __align__(16) ushort pool[2][128][64];   // Al/Bl, then Xl[128][128]
    const int hp = blockIdx.y;                 // head pair 0..3
    const int m0 = blockIdx.x * 128, n0 = hp * 128;
    const int t = threadIdx.x, l = t & 63, w = t >> 6;
    const int wr = w >> 1, wc = w & 1;
    const int lr = l & 15, lq = l >> 4;
    const float LOG2E = 1.4426950408889634f;
    const float LN2   = 0.6931471805599453f;
    const float SH2   = 36.0673760222f;        // 25*log2e

    // ---------------- phase 1: xmid GEMM (K=256) ----------------
    f32x4 acc[4][4];
    #pragma unroll
    for (int mi = 0; mi < 4; ++mi)
        #pragma unroll
        for (int ni = 0; ni < 4; ++ni) acc[mi][ni] = (f32x4){0.f, 0.f, 0.f, 0.f};

    for (int ks = 0; ks < 4; ++ks) {
        __syncthreads();
        #pragma unroll
        for (int i = 0; i < 4; ++i) {
            int idx = i * 256 + t;             // 0..1023
            int row = idx >> 3, g = idx & 7;
            ushort8 av = *(const ushort8*)&A[(size_t)(m0 + row) * 256 + ks * 64 + g * 8];
            *(ushort8*)&pool[0][row][(g ^ (row & 7)) * 8] = av;
            ushort8 bv = *(const ushort8*)&B[(size_t)(n0 + row) * 256 + ks * 64 + g * 8];
            *(ushort8*)&pool[1][row][(g ^ (row & 7)) * 8] = bv;
        }
        __syncthreads();
        #pragma unroll
        for (int kf = 0; kf < 2; ++kf) {
            short8 af[4], bfr[4];
            #pragma unroll
            for (int mi = 0; mi < 4; ++mi) {
                int row = wr * 64 + mi * 16 + lr, g = kf * 4 + lq;
                af[mi] = *(const short8*)&pool[0][row][(g ^ (row & 7)) * 8];
            }
            #pragma unroll
            for (int ni = 0; ni < 4; ++ni) {
                int row = wc * 64 + ni * 16 + lr, g = kf * 4 + lq;
                bfr[ni] = *(const short8*)&pool[1][row][(g ^ (row & 7)) * 8];
            }
            #pragma unroll
            for (int mi = 0; mi < 4; ++mi)
                #pragma unroll
                for (int ni = 0; ni < 4; ++ni)
                    acc[mi][ni] = __builtin_amdgcn_mfma_f32_16x16x32_bf16(
                        af[mi], bfr[ni], acc[mi][ni], 0, 0, 0);
        }
    }

    // ---------------- xmid tile -> LDS (Xl) + global xmb ----------------
    __syncthreads();                            // all frag reads of pool done
    ushort (* __restrict__ Xl)[128] = (ushort (*)[128])(&pool[0][0][0]);
    #pragma unroll
    for (int ni = 0; ni < 4; ++ni) {
        int colL = wc * 64 + ni * 16 + lr;      // local col 0..127
        float bb = bias[n0 + colL];
        int gg = colL >> 3, c7 = colL & 7;
        #pragma unroll
        for (int mi = 0; mi < 4; ++mi)
            #pragma unroll
            for (int j = 0; j < 4; ++j) {
                int row = wr * 64 + mi * 16 + lq * 4 + j;
                Xl[row][(gg ^ (row & 7)) * 8 + c7] = f2bf(acc[mi][ni][j] + bb);
            }
    }
    __syncthreads();
    // vectorized copy-out to xmb (coalesced 16B stores)
    #pragma unroll
    for (int i = 0; i < 8; ++i) {
        int e = i * 256 + t;                    // 0..2047
        int row = e >> 4, gg = e & 15;
        ushort8 v = *(const ushort8*)&Xl[row][(gg ^ (row & 7)) * 8];
        *(ushort8*)&xmb[(size_t)(m0 + row) * 512 + n0 + gg * 8] = v;
    }

    // ---------------- phase 2: lgt1 per head ----------------
    const float bt2v = bt2[0];
    float bsr[4], bt1r[4], wt2r[4];
    #pragma unroll
    for (int ni = 0; ni < 4; ++ni) {
        bsr[ni]  = bs [ni * 16 + lr];
        bt1r[ni] = bt1[ni * 16 + lr];
        wt2r[ni] = Wt2[ni * 16 + lr];
    }

    #pragma unroll
    for (int hh = 0; hh < 2; ++hh) {
        const int h = hp * 2 + hh;
        const float biasph = biasp[h];

        f32x4 acc2[2][8];
        #pragma unroll
        for (int mi = 0; mi < 2; ++mi)
            #pragma unroll
            for (int ni = 0; ni < 8; ++ni) acc2[mi][ni] = (f32x4){0.f, 0.f, 0.f, 0.f};

        #pragma unroll
        for (int kf = 0; kf < 2; ++kf) {
            const int g = kf * 4 + lq;
            short8 af[2], bfr[8];
            #pragma unroll
            for (int mi = 0; mi < 2; ++mi) {
                int row = w * 32 + mi * 16 + lr;
                int gg = hh * 8 + g;
                af[mi] = *(const short8*)&Xl[row][(gg ^ (row & 7)) * 8];
            }
            #pragma unroll
            for (int ni = 0; ni < 8; ++ni)      // direct from global wb (L2-hot)
                bfr[ni] = *(const short8*)&wb[(size_t)(ni * 16 + lr) * 64 + g * 8];
            #pragma unroll
            for (int mi = 0; mi < 2; ++mi)
                #pragma unroll
                for (int ni = 0; ni < 8; ++ni)
                    acc2[mi][ni] = __builtin_amdgcn_mfma_f32_16x16x32_bf16(
                        af[mi], bfr[ni], acc2[mi][ni], 0, 0, 0);
        }

        #pragma unroll
        for (int mi = 0; mi < 2; ++mi) {
            // just-in-time u loads (partially hidden under the gelu chains)
            float uu[4][4];
            #pragma unroll
            for (int jj = 0; jj < 4; ++jj) {
                const int n = m0 + w * 32 + mi * 16 + lq * 4 + jj;
                const float* up = &u[((size_t)h * NPTS + n) * 64 + lr];
                #pragma unroll
                for (int ni = 0; ni < 4; ++ni) uu[jj][ni] = up[ni * 16];
            }
            // temp-MLP (t1 cols = ni 4..7)
            float ts[4];
            #pragma unroll
            for (int jj = 0; jj < 4; ++jj) {
                float s = 0.f;
                #pragma unroll
                for (int ni = 0; ni < 4; ++ni)
                    s += gelu_fast(acc2[mi][ni + 4][jj] + bt1r[ni]) * wt2r[ni];
                ts[jj] = s;
            }
            #pragma unroll
            for (int off = 1; off <= 8; off <<= 1) {
                #pragma unroll
                for (int jj = 0; jj < 4; ++jj) ts[jj] += __shfl_xor(ts[jj], off);
            }
            float invt[4], invt2[4];
            #pragma unroll
            for (int jj = 0; jj < 4; ++jj) {
                float tmp = gelu_fast(ts[jj] + bt2v) + biasph;
                tmp = fmaxf(tmp, 0.01f);
                invt[jj]  = __builtin_amdgcn_rcpf(tmp);
                invt2[jj] = invt[jj] * LOG2E;
            }
            float sv[4][4], ps[4] = {0.f, 0.f, 0.f, 0.f};
            #pragma unroll
            for (int jj = 0; jj < 4; ++jj) {
                #pragma unroll
                for (int ni = 0; ni < 4; ++ni) {
                    float L1 = __log2f(uu[jj][ni] + 1e-8f);
                    float inner = fmaf(-LN2, L1, 1e-8f);
                    float L2v = __log2f(inner);
                    float base = fmaf(acc2[mi][ni][jj] + bsr[ni], invt2[jj], -SH2);
                    sv[jj][ni] = __builtin_amdgcn_exp2f(fmaf(-invt[jj], L2v, base));
                    ps[jj] += sv[jj][ni];
                }
            }
            #pragma unroll
            for (int off = 1; off <= 8; off <<= 1) {
                #pragma unroll
                for (int jj = 0; jj < 4; ++jj) ps[jj] += __shfl_xor(ps[jj], off);
            }
            #pragma unroll
            for (int jj = 0; jj < 4; ++jj) {
                const int n = m0 + w * 32 + mi * 16 + lq * 4 + jj;
                const float inv = __builtin_amdgcn_rcpf(ps[jj]);
                ushort* sp = &swb[(size_t)n * 512 + h * 64 + lr];
                #pragma unroll
                for (int ni = 0; ni < 4; ++ni)
                    sp[ni * 16] = f2bf(sv[jj][ni] * inv);
            }
        }
    }
}

// ---------------------------------------------------------------------------
// Stage 3 (MFMA): per (h, 1024-pt chunk): C[g][c] = sum_n sw[n][g]*x[n][c]
// Cross-wave reduce via LDS (single contiguous `tile` array).
// ---------------------------------------------------------------------------
__global__ __launch_bounds__(256)
void gather_mfma_kernel(const ushort* __restrict__ xmb, const ushort* __restrict__ swb,
                        float* __restrict__ stp, float* __restrict__ normp) {
    __shared__ __align__(16) ushort tile[2][64][128];   // [0]=swT, [1]=xT
    ushort (* __restrict__ swT)[128] = tile[0];
    ushort (* __restrict__ xT )[128] = tile[1];
    const int h  = blockIdx.y;
    const int n0 = blockIdx.x * 1024;
    const int t  = threadIdx.x, l = t & 63, w = t >> 6;
    const int lr = l & 15, lq = l >> 4;
    const int gb = t & 7;
    const int ng = t >> 3;

    f32x4 acc[4][4];
    #pragma unroll
    for (int gi = 0; gi < 4; ++gi)
        #pragma unroll
        for (int ci = 0; ci < 4; ++ci) acc[gi][ci] = (f32x4){0.f, 0.f, 0.f, 0.f};
    float nrm8[8];
    #pragma unroll
    for (int j = 0; j < 8; ++j) nrm8[j] = 0.f;

    for (int r = 0; r < 8; ++r) {
        const int nt = n0 + r * 128;
        ushort8 sv[4], xv[4];
        #pragma unroll
        for (int i = 0; i < 4; ++i) {
            int n = nt + ng * 4 + i;
            sv[i] = *(const ushort8*)&swb[(size_t)n * 512 + h * 64 + gb * 8];
            xv[i] = *(const ushort8*)&xmb[(size_t)n * 512 + h * 64 + gb * 8];
        }
        __syncthreads();
        #pragma unroll
        for (int j = 0; j < 8; ++j) {
            int g   = gb * 8 + j;
            int swz = (ng >> 1) ^ (g & 7) ^ ((g >> 3) & 7);
            int off = swz * 8 + (ng & 1) * 4;
            us4 s4 = { sv[0][j], sv[1][j], sv[2][j], sv[3][j] };
            us4 x4 = { xv[0][j], xv[1][j], xv[2][j], xv[3][j] };
            *(us4*)&swT[g][off] = s4;
            *(us4*)&xT [g][off] = x4;
            nrm8[j] += (bf2f(sv[0][j]) + bf2f(sv[1][j]))
                     + (bf2f(sv[2][j]) + bf2f(sv[3][j]));
        }
        __syncthreads();
        short8 af[4], bfr[4];
        #pragma unroll
        for (int gi = 0; gi < 4; ++gi) {
            int g   = gi * 16 + lr;
            int swz = (w * 4 + lq) ^ (g & 7) ^ ((g >> 3) & 7);
            af[gi]  = *(const short8*)&swT[g][swz * 8];
            bfr[gi] = *(const short8*)&xT [g][swz * 8];
        }
        #pragma unroll
        for (int gi = 0; gi < 4; ++gi)
            #pragma unroll
            for (int ci = 0; ci < 4; ++ci)
                acc[gi][ci] = __builtin_amdgcn_mfma_f32_16x16x32_bf16(
                    af[gi], bfr[ci], acc[gi][ci], 0, 0, 0);
    }

    // cross-wave reduce via LDS: sred[4][32][64] f32 = 32KB (contiguous)
    float* sred = (float*)tile;
    const size_t stbase = ((size_t)h * 64 + blockIdx.x) * 4096;
    #pragma unroll
    for (int half = 0; half < 2; ++half) {
        __syncthreads();
        #pragma unroll
        for (int gg = 0; gg < 2; ++gg) {
            int gi = half * 2 + gg;
            #pragma unroll
            for (int ci = 0; ci < 4; ++ci)
                #pragma unroll
                for (int j = 0; j < 4; ++j)
                    sred[(w * 32 + gg * 16 + lq * 4 + j) * 64 + ci * 16 + lr]
                        = acc[gi][ci][j];
        }
        __syncthreads();
        #pragma unroll
        for (int i = 0; i < 8; ++i) {
            int e = i * 256 + t;            // 0..2047
            float s = (sred[e] + sred[2048 + e]) + (sred[4096 + e] + sred[6144 + e]);
            stp[stbase + half * 2048 + e] = s;
        }
    }

    __syncthreads();
    float* narr = (float*)tile;
    #pragma unroll
    for (int j = 0; j < 8; ++j) narr[ng * 64 + gb * 8 + j] = nrm8[j];
    __syncthreads();
    if (t < 64) {
        float s = 0.f;
        #pragma unroll 8
        for (int k = 0; k < 32; ++k) s += narr[k * 64 + t];
        normp[((size_t)h * 64 + blockIdx.x) * 64 + t] = s;
    }
}

// ---------------------------------------------------------------------------
// Stage 4a: reduce chunk partials -> st_red, nrm
// ---------------------------------------------------------------------------
__global__ __launch_bounds__(256)
void reduce_st_kernel(const float* __restrict__ stp, const float* __restrict__ normp,
                      float* __restrict__ st_red, float* __restrict__ nrm) {
    const int h = blockIdx.x;
    const int e = blockIdx.y * 256 + threadIdx.x;
    float s = 0.f;
    #pragma unroll 8
    for (int ch = 0; ch < 64; ++ch)
        s += stp[((size_t)h * 64 + ch) * 4096 + e];
    st_red[(size_t)h * 4096 + e] = s;
    if (blockIdx.y == 0 && threadIdx.x < 64) {
        float ns = 0.f;
        #pragma unroll 8
        for (int ch = 0; ch < 64; ++ch)
            ns += normp[((size_t)h * 64 + ch) * 64 + threadIdx.x];
        nrm[h * 64 + threadIdx.x] = ns + 1e-5f;
    }
}

// ---------------------------------------------------------------------------
// Stage 4b: per head: normalize tokens, qkv, 64x64 attention -> osl
// ---------------------------------------------------------------------------
__global__ __launch_bounds__(256)
void attn_small_kernel(const float* __restrict__ st_red, const float* __restrict__ nrm,
                       const float* __restrict__ Wq, const float* __restrict__ Wk,
                       const float* __restrict__ Wv, float* __restrict__ osl) {
    __shared__ float st[64][68];
    __shared__ float ql[64][68];
    __shared__ float kl[64][68];
    __shared__ float vl[64][68];
    __shared__ float sc[64][68];
    __shared__ float nl[64];
    const int h = blockIdx.x;
    const int t = threadIdx.x;

    if (t < 64) nl[t] = nrm[h * 64 + t];
    __syncthreads();
    for (int e = t; e < 4096; e += 256)
        st[e>>6][e&63] = st_red[(size_t)h * 4096 + e] / nl[e>>6];
    __syncthreads();
    for (int e = t; e < 4096; e += 256) {
        int g = e >> 6, dd = e & 63;
        float aq = 0.f, ak = 0.f, av = 0.f;
        for (int cc = 0; cc < 64; ++cc) {
            float sv = st[g][cc];
            aq = fmaf(sv, Wq[dd*64 + cc], aq);
            ak = fmaf(sv, Wk[dd*64 + cc], ak);
            av = fmaf(sv, Wv[dd*64 + cc], av);
        }
        ql[g][dd] = aq; kl[g][dd] = ak; vl[g][dd] = av;
    }
    __syncthreads();
    for (int e = t; e < 4096; e += 256) {
        int g = e >> 6, gp = e & 63;
        float s = 0.f;
        for (int dd = 0; dd < 64; ++dd) s = fmaf(ql[g][dd], kl[gp][dd], s);
        sc[g][gp] = s * 0.125f;
    }
    __syncthreads();
    if (t < 64) {
        float m = -1e30f;
        for (int j = 0; j < 64; ++j) m = fmaxf(m, sc[t][j]);
        float ssum = 0.f;
        for (int j = 0; j < 64; ++j) { float p = expf(sc[t][j] - m); sc[t][j] = p; ssum += p; }
        float inv = 1.f / ssum;
        for (int j = 0; j < 64; ++j) sc[t][j] *= inv;
    }
    __syncthreads();
    for (int e = t; e < 4096; e += 256) {
        int g = e >> 6, dd = e & 63;
        float s = 0.f;
        for (int gp = 0; gp < 64; ++gp) s = fmaf(sc[g][gp], vl[gp][dd], s);
        osl[(size_t)h * 4096 + e] = s;
    }
}

// ---------------------------------------------------------------------------
// Stage 4c: fold out_slice into Wout: Mtb[i][h*64+g] (bf16 output)
// ---------------------------------------------------------------------------
__global__ __launch_bounds__(256)
void fold_kernel(const float* __restrict__ osl, const float* __restrict__ Wout,
                 ushort* __restrict__ Mtb) {
    __shared__ float os[64][65];
    __shared__ float wl[128][65];
    const int h  = blockIdx.x;
    const int i0 = blockIdx.y * 128;
    const int t  = threadIdx.x;
    for (int e = t; e < 4096; e += 256) os[e>>6][e&63] = osl[(size_t)h * 4096 + e];
    for (int e = t; e < 8192; e += 256) {
        int i = e >> 6, d = e & 63;
        wl[i][d] = Wout[(size_t)(i0 + i) * HDIM + h * 64 + d];
    }
    __syncthreads();
    const int g = t & 63, iq = t >> 6;
    #pragma unroll 4
    for (int k = 0; k < 32; ++k) {
        int i = iq * 32 + k;
        float s = 0.f;
        #pragma unroll
        for (int d = 0; d < 64; ++d) s = fmaf(os[g][d], wl[i][d], s);
        Mtb[(size_t)(i0 + i) * HDIM + h * 64 + g] = f2bf(s);
    }
}

// ---------------------------------------------------------------------------
// Stage 5: out_f32[M][256] = swb_bf16[M][512] @ Mtb^T + bout  (128x128 tile,
// grid 1024 flat, adjacent-pair A-sharing)
// ---------------------------------------------------------------------------
__global__ __launch_bounds__(256)
void gemm_out_kernel(const ushort* __restrict__ A, const ushort* __restrict__ B,
                     const float* __restrict__ bias, float* __restrict__ C) {
    __shared__ __align__(16) ushort Al[128][64];
    __shared__ __align__(16) ushort Bl[128][64];
    const int bid = blockIdx.x;
    const int m0 = (bid >> 1) * 128, n0 = (bid & 1) * 128;
    const int t = threadIdx.x, l = t & 63, w = t >> 6;
    const int wr = w >> 1, wc = w & 1;
    const int lr = l & 15, lq = l >> 4;

    f32x4 acc[4][4];
    #pragma unroll
    for (int mi = 0; mi < 4; ++mi)
        #pragma unroll
        for (int ni = 0; ni < 4; ++ni) acc[mi][ni] = (f32x4){0.f, 0.f, 0.f, 0.f};

    for (int ks = 0; ks < 8; ++ks) {          // K-step of 64 (K=512)
        __syncthreads();
        #pragma unroll
        for (int i = 0; i < 4; ++i) {
            int idx = i * 256 + t;
            int row = idx >> 3, g = idx & 7;
            ushort8 av = *(const ushort8*)&A[(size_t)(m0 + row) * 512 + ks * 64 + g * 8];
            *(ushort8*)&Al[row][(g ^ (row & 7)) * 8] = av;
            ushort8 bv = *(const ushort8*)&B[(size_t)(n0 + row) * 512 + ks * 64 + g * 8];
            *(ushort8*)&Bl[row][(g ^ (row & 7)) * 8] = bv;
        }
        __syncthreads();
        #pragma unroll
        for (int kf = 0; kf < 2; ++kf) {
            short8 af[4], bfr[4];
            #pragma unroll
            for (int mi = 0; mi < 4; ++mi) {
                int row = wr * 64 + mi * 16 + lr, g = kf * 4 + lq;
                af[mi] = *(const short8*)&Al[row][(g ^ (row & 7)) * 8];
            }
            #pragma unroll
            for (int ni = 0; ni < 4; ++ni) {
                int row = wc * 64 + ni * 16 + lr, g = kf * 4 + lq;
                bfr[ni] = *(const short8*)&Bl[row][(g ^ (row & 7)) * 8];
            }
            #pragma unroll
            for (int mi = 0; mi < 4; ++mi)
                #pragma unroll
                for (int ni = 0; ni < 4; ++ni)
                    acc[mi][ni] = __builtin_amdgcn_mfma_f32_16x16x32_bf16(
                        af[mi], bfr[ni], acc[mi][ni], 0, 0, 0);
        }
    }
    #pragma unroll
    for (int ni = 0; ni < 4; ++ni) {
        int col = n0 + wc * 64 + ni * 16 + lr;
        float bb = bias[col];
        #pragma unroll
        for (int mi = 0; mi < 4; ++mi)
            #pragma unroll
            for (int j = 0; j < 4; ++j) {
                int row = m0 + wr * 64 + mi * 16 + lq * 4 + j;
                C[(size_t)row * 256 + col] = acc[mi][ni][j] + bb;
            }
    }
}

// ---------------------------------------------------------------------------
extern "C" void kernel_launch(void* const* d_in, const int* in_sizes, int n_in,
                              void* d_out, int out_size, void* d_ws, size_t ws_size,
                              hipStream_t stream) {
    const float* x    = (const float*)d_in[0];
    const float* Wx   = (const float*)d_in[1];
    const float* bx   = (const float*)d_in[2];
    const float* Wt1  = (const float*)d_in[3];
    const float* bt1  = (const float*)d_in[4];
    const float* Wt2  = (const float*)d_in[5];
    const float* bt2  = (const float*)d_in[6];
    const float* biasp= (const float*)d_in[7];
    const float* Ws   = (const float*)d_in[8];
    const float* bs   = (const float*)d_in[9];
    const float* Wq   = (const float*)d_in[10];
    const float* Wk   = (const float*)d_in[11];
    const float* Wv   = (const float*)d_in[12];
    const float* Wout = (const float*)d_in[13];
    const float* bout = (const float*)d_in[14];
    const float* u    = (const float*)d_in[15];
    float* out = (float*)d_out;

    float*  stp    = (float*)d_ws;                           // 8*64*4096 f32 = 8.4 MB
    float*  normp  = stp    + (size_t)NH * 64 * 4096;        // 8*64*64
    float*  st_red = normp  + (size_t)NH * 64 * 64;          // 8*4096
    float*  nrm    = st_red + (size_t)NH * 4096;             // 8*64
    float*  osl    = nrm    + (size_t)NH * 64;               // 8*4096
    ushort* wb     = (ushort*)(osl + (size_t)NH * 4096);     // 128*64 bf16
    ushort* Wxb    = wb  + (size_t)128 * 64;                 // 512*256 bf16
    ushort* Mtb    = Wxb + (size_t)HDIM * DIMX;              // 256*512 bf16
    ushort* xb     = Mtb + (size_t)DIMX * HDIM;              // 65536*256 bf16
    ushort* xmb    = xb  + (size_t)NPTS * DIMX;              // 65536*512 bf16
    ushort* swb    = xmb + (size_t)NPTS * HDIM;              // 65536*512 bf16

    // 0) pre-convert x, Wx and [Ws;Wt1] to bf16
    prep_kernel<<<8260, 256, 0, stream>>>(x, Wx, Ws, Wt1, xb, Wxb, wb);
    // 1+2) fused: xmid GEMM + logits/temp GEMM + gumbel softmax
    xmid_lgt1_kernel<<<dim3(512, 4), 256, 0, stream>>>(xb, Wxb, bx, wb, bs, bt1,
                                                       Wt2, bt2, biasp, u,
                                                       xmb, swb);
    // 3) slice token partials via MFMA (in-block cross-wave reduce)
    gather_mfma_kernel<<<dim3(64, 8), 256, 0, stream>>>(xmb, swb, stp, normp);
    // 4a) reduce partials
    reduce_st_kernel<<<dim3(8, 16), 256, 0, stream>>>(stp, normp, st_red, nrm);
    // 4b) tiny attention
    attn_small_kernel<<<8, 256, 0, stream>>>(st_red, nrm, Wq, Wk, Wv, osl);
    // 4c) fold out_slice into Wout (bf16 output)
    fold_kernel<<<dim3(8, 2), 256, 0, stream>>>(osl, Wout, Mtb);
    // 5) out = sw @ Mtb^T + bout (adjacent-pair A-sharing, grid 1024)
    gemm_out_kernel<<<dim3(1024), 256, 0, stream>>>(swb, Mtb, bout, out);
}

// Round 20
// 259.362 us; speedup vs baseline: 1.0119x; 1.0119x over previous
//
#include <hip/hip_runtime.h>
#include <math.h>

// Physics_Attention: B=1, N=65536, DIM=256, H=8, D=64, G=64
#define NPTS  65536
#define DIMX  256
#define NH    8
#define HDIM  512   // H*D

typedef __attribute__((ext_vector_type(4))) float f32x4;
typedef __attribute__((ext_vector_type(8))) short short8;
typedef __attribute__((ext_vector_type(8))) unsigned short ushort8;
typedef __attribute__((ext_vector_type(4))) unsigned short us4;

__device__ __forceinline__ ushort f2bf(float f) {   // RNE f32->bf16
    unsigned x = __float_as_uint(f);
    return (ushort)((x + 0x7fffu + ((x >> 16) & 1u)) >> 16);
}
__device__ __forceinline__ float bf2f(ushort u) {
    return __uint_as_float((unsigned)u << 16);
}
// Fast erf (A&S 7.1.26, abs err 1.5e-7) — no branches, HW exp/rcp
__device__ __forceinline__ float erf_fast(float x) {
    float ax = fabsf(x);
    float t  = __builtin_amdgcn_rcpf(1.0f + 0.3275911f * ax);
    float p  = fmaf(fmaf(fmaf(fmaf(1.061405429f, t, -1.453152027f), t,
                   1.421413741f), t, -0.284496736f), t, 0.254829592f) * t;
    float y  = 1.0f - p * __expf(-ax * ax);
    return copysignf(y, x);
}
__device__ __forceinline__ float gelu_fast(float x) {
    return 0.5f * x * (1.0f + erf_fast(x * 0.7071067811865476f));
}

// ---------------------------------------------------------------------------
// Stage 0: pre-convert x (65536x256), Wx (512x256), [Ws;Wt1] (128x64) to bf16.
// ---------------------------------------------------------------------------
__global__ __launch_bounds__(256)
void prep_kernel(const float* __restrict__ x, const float* __restrict__ Wx,
                 const float* __restrict__ Ws, const float* __restrict__ Wt1,
                 ushort* __restrict__ xb, ushort* __restrict__ Wxb,
                 ushort* __restrict__ wb) {
    const int t = threadIdx.x;
    const int b = blockIdx.x;
    if (b < 8192) {
        size_t idx = (size_t)b * 2048 + t * 8;
        float4 a0 = *(const float4*)&x[idx];
        float4 a1 = *(const float4*)&x[idx + 4];
        ushort8 v = { f2bf(a0.x), f2bf(a0.y), f2bf(a0.z), f2bf(a0.w),
                      f2bf(a1.x), f2bf(a1.y), f2bf(a1.z), f2bf(a1.w) };
        *(ushort8*)&xb[idx] = v;
    } else if (b < 8256) {
        int idx = (b - 8192) * 2048 + t * 8;
        float4 a0 = *(const float4*)&Wx[idx];
        float4 a1 = *(const float4*)&Wx[idx + 4];
        ushort8 v = { f2bf(a0.x), f2bf(a0.y), f2bf(a0.z), f2bf(a0.w),
                      f2bf(a1.x), f2bf(a1.y), f2bf(a1.z), f2bf(a1.w) };
        *(ushort8*)&Wxb[idx] = v;
    } else {
        int idx = (b - 8256) * 2048 + t * 8;   // 0..8191
        int row = idx >> 6, col = idx & 63;
        const float* src = (row < 64) ? &Ws[row * 64 + col]
                                      : &Wt1[(row - 64) * 64 + col];
        float4 a0 = *(const float4*)src;
        float4 a1 = *(const float4*)(src + 4);
        ushort8 v = { f2bf(a0.x), f2bf(a0.y), f2bf(a0.z), f2bf(a0.w),
                      f2bf(a1.x), f2bf(a1.y), f2bf(a1.z), f2bf(a1.w) };
        *(ushort8*)&wb[idx] = v;
    }
}

// ---------------------------------------------------------------------------
// Stage 1+2 FUSED (round-12 structure; bf16 xb input; default occupancy —
// round-19 lesson: forcing 3 waves/SIMD raised occupancy 21->28% with ZERO
// time change; the kernel is critical-path-bound, not TLP-bound):
//   xmid tile via MFMA (K=256) -> bf16 LDS Xl + vectorized xmb copy-out,
//   then per head: [lg|t1] GEMM (A from Xl, B from L2-hot wb), JIT u loads,
//   temp-MLP + gumbel softmax epilogue -> swb.
// ---------------------------------------------------------------------------
__global__ __launch_bounds__(256)
void xmid_lgt1_kernel(const ushort* __restrict__ A, const ushort* __restrict__ B,
                      const float* __restrict__ bias,
                      const ushort* __restrict__ wb,
                      const float* __restrict__ bs,  const float* __restrict__ bt1,
                      const float* __restrict__ Wt2, const float* __restrict__ bt2,
                      const float* __restrict__ biasp,
                      const float* __restrict__ u,
                      ushort* __restrict__ xmb, ushort* __restrict__ swb) {
    __shared__ __align__(16) ushort pool[2][128][64];   // Al/Bl, then Xl[128][128]
    const int hp = blockIdx.y;                 // head pair 0..3
    const int m0 = blockIdx.x * 128, n0 = hp * 128;
    const int t = threadIdx.x, l = t & 63, w = t >> 6;
    const int wr = w >> 1, wc = w & 1;
    const int lr = l & 15, lq = l >> 4;
    const float LOG2E = 1.4426950408889634f;
    const float LN2   = 0.6931471805599453f;
    const float SH2   = 36.0673760222f;        // 25*log2e

    // ---------------- phase 1: xmid GEMM (K=256) ----------------
    f32x4 acc[4][4];
    #pragma unroll
    for (int mi = 0; mi < 4; ++mi)
        #pragma unroll
        for (int ni = 0; ni < 4; ++ni) acc[mi][ni] = (f32x4){0.f, 0.f, 0.f, 0.f};

    for (int ks = 0; ks < 4; ++ks) {
        __syncthreads();
        #pragma unroll
        for (int i = 0; i < 4; ++i) {
            int idx = i * 256 + t;             // 0..1023
            int row = idx >> 3, g = idx & 7;
            ushort8 av = *(const ushort8*)&A[(size_t)(m0 + row) * 256 + ks * 64 + g * 8];
            *(ushort8*)&pool[0][row][(g ^ (row & 7)) * 8] = av;
            ushort8 bv = *(const ushort8*)&B[(size_t)(n0 + row) * 256 + ks * 64 + g * 8];
            *(ushort8*)&pool[1][row][(g ^ (row & 7)) * 8] = bv;
        }
        __syncthreads();
        #pragma unroll
        for (int kf = 0; kf < 2; ++kf) {
            short8 af[4], bfr[4];
            #pragma unroll
            for (int mi = 0; mi < 4; ++mi) {
                int row = wr * 64 + mi * 16 + lr, g = kf * 4 + lq;
                af[mi] = *(const short8*)&pool[0][row][(g ^ (row & 7)) * 8];
            }
            #pragma unroll
            for (int ni = 0; ni < 4; ++ni) {
                int row = wc * 64 + ni * 16 + lr, g = kf * 4 + lq;
                bfr[ni] = *(const short8*)&pool[1][row][(g ^ (row & 7)) * 8];
            }
            #pragma unroll
            for (int mi = 0; mi < 4; ++mi)
                #pragma unroll
                for (int ni = 0; ni < 4; ++ni)
                    acc[mi][ni] = __builtin_amdgcn_mfma_f32_16x16x32_bf16(
                        af[mi], bfr[ni], acc[mi][ni], 0, 0, 0);
        }
    }

    // ---------------- xmid tile -> LDS (Xl) + global xmb ----------------
    __syncthreads();                            // all frag reads of pool done
    ushort (* __restrict__ Xl)[128] = (ushort (*)[128])(&pool[0][0][0]);
    #pragma unroll
    for (int ni = 0; ni < 4; ++ni) {
        int colL = wc * 64 + ni * 16 + lr;      // local col 0..127
        float bb = bias[n0 + colL];
        int gg = colL >> 3, c7 = colL & 7;
        #pragma unroll
        for (int mi = 0; mi < 4; ++mi)
            #pragma unroll
            for (int j = 0; j < 4; ++j) {
                int row = wr * 64 + mi * 16 + lq * 4 + j;
                Xl[row][(gg ^ (row & 7)) * 8 + c7] = f2bf(acc[mi][ni][j] + bb);
            }
    }
    __syncthreads();
    // vectorized copy-out to xmb (coalesced 16B stores)
    #pragma unroll
    for (int i = 0; i < 8; ++i) {
        int e = i * 256 + t;                    // 0..2047
        int row = e >> 4, gg = e & 15;
        ushort8 v = *(const ushort8*)&Xl[row][(gg ^ (row & 7)) * 8];
        *(ushort8*)&xmb[(size_t)(m0 + row) * 512 + n0 + gg * 8] = v;
    }

    // ---------------- phase 2: lgt1 per head ----------------
    const float bt2v = bt2[0];
    float bsr[4], bt1r[4], wt2r[4];
    #pragma unroll
    for (int ni = 0; ni < 4; ++ni) {
        bsr[ni]  = bs [ni * 16 + lr];
        bt1r[ni] = bt1[ni * 16 + lr];
        wt2r[ni] = Wt2[ni * 16 + lr];
    }

    #pragma unroll
    for (int hh = 0; hh < 2; ++hh) {
        const int h = hp * 2 + hh;
        const float biasph = biasp[h];

        f32x4 acc2[2][8];
        #pragma unroll
        for (int mi = 0; mi < 2; ++mi)
            #pragma unroll
            for (int ni = 0; ni < 8; ++ni) acc2[mi][ni] = (f32x4){0.f, 0.f, 0.f, 0.f};

        #pragma unroll
        for (int kf = 0; kf < 2; ++kf) {
            const int g = kf * 4 + lq;
            short8 af[2], bfr[8];
            #pragma unroll
            for (int mi = 0; mi < 2; ++mi) {
                int row = w * 32 + mi * 16 + lr;
                int gg = hh * 8 + g;
                af[mi] = *(const short8*)&Xl[row][(gg ^ (row & 7)) * 8];
            }
            #pragma unroll
            for (int ni = 0; ni < 8; ++ni)      // direct from global wb (L2-hot)
                bfr[ni] = *(const short8*)&wb[(size_t)(ni * 16 + lr) * 64 + g * 8];
            #pragma unroll
            for (int mi = 0; mi < 2; ++mi)
                #pragma unroll
                for (int ni = 0; ni < 8; ++ni)
                    acc2[mi][ni] = __builtin_amdgcn_mfma_f32_16x16x32_bf16(
                        af[mi], bfr[ni], acc2[mi][ni], 0, 0, 0);
        }

        #pragma unroll
        for (int mi = 0; mi < 2; ++mi) {
            // just-in-time u loads (partially hidden under the gelu chains)
            float uu[4][4];
            #pragma unroll
            for (int jj = 0; jj < 4; ++jj) {
                const int n = m0 + w * 32 + mi * 16 + lq * 4 + jj;
                const float* up = &u[((size_t)h * NPTS + n) * 64 + lr];
                #pragma unroll
                for (int ni = 0; ni < 4; ++ni) uu[jj][ni] = up[ni * 16];
            }
            // temp-MLP (t1 cols = ni 4..7)
            float ts[4];
            #pragma unroll
            for (int jj = 0; jj < 4; ++jj) {
                float s = 0.f;
                #pragma unroll
                for (int ni = 0; ni < 4; ++ni)
                    s += gelu_fast(acc2[mi][ni + 4][jj] + bt1r[ni]) * wt2r[ni];
                ts[jj] = s;
            }
            #pragma unroll
            for (int off = 1; off <= 8; off <<= 1) {
                #pragma unroll
                for (int jj = 0; jj < 4; ++jj) ts[jj] += __shfl_xor(ts[jj], off);
            }
            float invt[4], invt2[4];
            #pragma unroll
            for (int jj = 0; jj < 4; ++jj) {
                float tmp = gelu_fast(ts[jj] + bt2v) + biasph;
                tmp = fmaxf(tmp, 0.01f);
                invt[jj]  = __builtin_amdgcn_rcpf(tmp);
                invt2[jj] = invt[jj] * LOG2E;
            }
            float sv[4][4], ps[4] = {0.f, 0.f, 0.f, 0.f};
            #pragma unroll
            for (int jj = 0; jj < 4; ++jj) {
                #pragma unroll
                for (int ni = 0; ni < 4; ++ni) {
                    float L1 = __log2f(uu[jj][ni] + 1e-8f);
                    float inner = fmaf(-LN2, L1, 1e-8f);
                    float L2v = __log2f(inner);
                    float base = fmaf(acc2[mi][ni][jj] + bsr[ni], invt2[jj], -SH2);
                    sv[jj][ni] = __builtin_amdgcn_exp2f(fmaf(-invt[jj], L2v, base));
                    ps[jj] += sv[jj][ni];
                }
            }
            #pragma unroll
            for (int off = 1; off <= 8; off <<= 1) {
                #pragma unroll
                for (int jj = 0; jj < 4; ++jj) ps[jj] += __shfl_xor(ps[jj], off);
            }
            #pragma unroll
            for (int jj = 0; jj < 4; ++jj) {
                const int n = m0 + w * 32 + mi * 16 + lq * 4 + jj;
                const float inv = __builtin_amdgcn_rcpf(ps[jj]);
                ushort* sp = &swb[(size_t)n * 512 + h * 64 + lr];
                #pragma unroll
                for (int ni = 0; ni < 4; ++ni)
                    sp[ni * 16] = f2bf(sv[jj][ni] * inv);
            }
        }
    }
}

// ---------------------------------------------------------------------------
// Stage 3 (MFMA): per (h, 1024-pt chunk): C[g][c] = sum_n sw[n][g]*x[n][c]
// Cross-wave reduce via LDS (single contiguous `tile` array).
// ---------------------------------------------------------------------------
__global__ __launch_bounds__(256)
void gather_mfma_kernel(const ushort* __restrict__ xmb, const ushort* __restrict__ swb,
                        float* __restrict__ stp, float* __restrict__ normp) {
    __shared__ __align__(16) ushort tile[2][64][128];   // [0]=swT, [1]=xT
    ushort (* __restrict__ swT)[128] = tile[0];
    ushort (* __restrict__ xT )[128] = tile[1];
    const int h  = blockIdx.y;
    const int n0 = blockIdx.x * 1024;
    const int t  = threadIdx.x, l = t & 63, w = t >> 6;
    const int lr = l & 15, lq = l >> 4;
    const int gb = t & 7;
    const int ng = t >> 3;

    f32x4 acc[4][4];
    #pragma unroll
    for (int gi = 0; gi < 4; ++gi)
        #pragma unroll
        for (int ci = 0; ci < 4; ++ci) acc[gi][ci] = (f32x4){0.f, 0.f, 0.f, 0.f};
    float nrm8[8];
    #pragma unroll
    for (int j = 0; j < 8; ++j) nrm8[j] = 0.f;

    for (int r = 0; r < 8; ++r) {
        const int nt = n0 + r * 128;
        ushort8 sv[4], xv[4];
        #pragma unroll
        for (int i = 0; i < 4; ++i) {
            int n = nt + ng * 4 + i;
            sv[i] = *(const ushort8*)&swb[(size_t)n * 512 + h * 64 + gb * 8];
            xv[i] = *(const ushort8*)&xmb[(size_t)n * 512 + h * 64 + gb * 8];
        }
        __syncthreads();
        #pragma unroll
        for (int j = 0; j < 8; ++j) {
            int g   = gb * 8 + j;
            int swz = (ng >> 1) ^ (g & 7) ^ ((g >> 3) & 7);
            int off = swz * 8 + (ng & 1) * 4;
            us4 s4 = { sv[0][j], sv[1][j], sv[2][j], sv[3][j] };
            us4 x4 = { xv[0][j], xv[1][j], xv[2][j], xv[3][j] };
            *(us4*)&swT[g][off] = s4;
            *(us4*)&xT [g][off] = x4;
            nrm8[j] += (bf2f(sv[0][j]) + bf2f(sv[1][j]))
                     + (bf2f(sv[2][j]) + bf2f(sv[3][j]));
        }
        __syncthreads();
        short8 af[4], bfr[4];
        #pragma unroll
        for (int gi = 0; gi < 4; ++gi) {
            int g   = gi * 16 + lr;
            int swz = (w * 4 + lq) ^ (g & 7) ^ ((g >> 3) & 7);
            af[gi]  = *(const short8*)&swT[g][swz * 8];
            bfr[gi] = *(const short8*)&xT [g][swz * 8];
        }
        #pragma unroll
        for (int gi = 0; gi < 4; ++gi)
            #pragma unroll
            for (int ci = 0; ci < 4; ++ci)
                acc[gi][ci] = __builtin_amdgcn_mfma_f32_16x16x32_bf16(
                    af[gi], bfr[ci], acc[gi][ci], 0, 0, 0);
    }

    // cross-wave reduce via LDS: sred[4][32][64] f32 = 32KB (contiguous)
    float* sred = (float*)tile;
    const size_t stbase = ((size_t)h * 64 + blockIdx.x) * 4096;
    #pragma unroll
    for (int half = 0; half < 2; ++half) {
        __syncthreads();
        #pragma unroll
        for (int gg = 0; gg < 2; ++gg) {
            int gi = half * 2 + gg;
            #pragma unroll
            for (int ci = 0; ci < 4; ++ci)
                #pragma unroll
                for (int j = 0; j < 4; ++j)
                    sred[(w * 32 + gg * 16 + lq * 4 + j) * 64 + ci * 16 + lr]
                        = acc[gi][ci][j];
        }
        __syncthreads();
        #pragma unroll
        for (int i = 0; i < 8; ++i) {
            int e = i * 256 + t;            // 0..2047
            float s = (sred[e] + sred[2048 + e]) + (sred[4096 + e] + sred[6144 + e]);
            stp[stbase + half * 2048 + e] = s;
        }
    }

    __syncthreads();
    float* narr = (float*)tile;
    #pragma unroll
    for (int j = 0; j < 8; ++j) narr[ng * 64 + gb * 8 + j] = nrm8[j];
    __syncthreads();
    if (t < 64) {
        float s = 0.f;
        #pragma unroll 8
        for (int k = 0; k < 32; ++k) s += narr[k * 64 + t];
        normp[((size_t)h * 64 + blockIdx.x) * 64 + t] = s;
    }
}

// ---------------------------------------------------------------------------
// Stage 4a: reduce chunk partials -> st_red, nrm
// ---------------------------------------------------------------------------
__global__ __launch_bounds__(256)
void reduce_st_kernel(const float* __restrict__ stp, const float* __restrict__ normp,
                      float* __restrict__ st_red, float* __restrict__ nrm) {
    const int h = blockIdx.x;
    const int e = blockIdx.y * 256 + threadIdx.x;
    float s = 0.f;
    #pragma unroll 8
    for (int ch = 0; ch < 64; ++ch)
        s += stp[((size_t)h * 64 + ch) * 4096 + e];
    st_red[(size_t)h * 4096 + e] = s;
    if (blockIdx.y == 0 && threadIdx.x < 64) {
        float ns = 0.f;
        #pragma unroll 8
        for (int ch = 0; ch < 64; ++ch)
            ns += normp[((size_t)h * 64 + ch) * 64 + threadIdx.x];
        nrm[h * 64 + threadIdx.x] = ns + 1e-5f;
    }
}

// ---------------------------------------------------------------------------
// Stage 4b: per head: normalize tokens, qkv, 64x64 attention -> osl
// ---------------------------------------------------------------------------
__global__ __launch_bounds__(256)
void attn_small_kernel(const float* __restrict__ st_red, const float* __restrict__ nrm,
                       const float* __restrict__ Wq, const float* __restrict__ Wk,
                       const float* __restrict__ Wv, float* __restrict__ osl) {
    __shared__ float st[64][68];
    __shared__ float ql[64][68];
    __shared__ float kl[64][68];
    __shared__ float vl[64][68];
    __shared__ float sc[64][68];
    __shared__ float nl[64];
    const int h = blockIdx.x;
    const int t = threadIdx.x;

    if (t < 64) nl[t] = nrm[h * 64 + t];
    __syncthreads();
    for (int e = t; e < 4096; e += 256)
        st[e>>6][e&63] = st_red[(size_t)h * 4096 + e] / nl[e>>6];
    __syncthreads();
    for (int e = t; e < 4096; e += 256) {
        int g = e >> 6, dd = e & 63;
        float aq = 0.f, ak = 0.f, av = 0.f;
        for (int cc = 0; cc < 64; ++cc) {
            float sv = st[g][cc];
            aq = fmaf(sv, Wq[dd*64 + cc], aq);
            ak = fmaf(sv, Wk[dd*64 + cc], ak);
            av = fmaf(sv, Wv[dd*64 + cc], av);
        }
        ql[g][dd] = aq; kl[g][dd] = ak; vl[g][dd] = av;
    }
    __syncthreads();
    for (int e = t; e < 4096; e += 256) {
        int g = e >> 6, gp = e & 63;
        float s = 0.f;
        for (int dd = 0; dd < 64; ++dd) s = fmaf(ql[g][dd], kl[gp][dd], s);
        sc[g][gp] = s * 0.125f;
    }
    __syncthreads();
    if (t < 64) {
        float m = -1e30f;
        for (int j = 0; j < 64; ++j) m = fmaxf(m, sc[t][j]);
        float ssum = 0.f;
        for (int j = 0; j < 64; ++j) { float p = expf(sc[t][j] - m); sc[t][j] = p; ssum += p; }
        float inv = 1.f / ssum;
        for (int j = 0; j < 64; ++j) sc[t][j] *= inv;
    }
    __syncthreads();
    for (int e = t; e < 4096; e += 256) {
        int g = e >> 6, dd = e & 63;
        float s = 0.f;
        for (int gp = 0; gp < 64; ++gp) s = fmaf(sc[g][gp], vl[gp][dd], s);
        osl[(size_t)h * 4096 + e] = s;
    }
}

// ---------------------------------------------------------------------------
// Stage 4c: fold out_slice into Wout: Mtb[i][h*64+g] (bf16 output)
// ---------------------------------------------------------------------------
__global__ __launch_bounds__(256)
void fold_kernel(const float* __restrict__ osl, const float* __restrict__ Wout,
                 ushort* __restrict__ Mtb) {
    __shared__ float os[64][65];
    __shared__ float wl[128][65];
    const int h  = blockIdx.x;
    const int i0 = blockIdx.y * 128;
    const int t  = threadIdx.x;
    for (int e = t; e < 4096; e += 256) os[e>>6][e&63] = osl[(size_t)h * 4096 + e];
    for (int e = t; e < 8192; e += 256) {
        int i = e >> 6, d = e & 63;
        wl[i][d] = Wout[(size_t)(i0 + i) * HDIM + h * 64 + d];
    }
    __syncthreads();
    const int g = t & 63, iq = t >> 6;
    #pragma unroll 4
    for (int k = 0; k < 32; ++k) {
        int i = iq * 32 + k;
        float s = 0.f;
        #pragma unroll
        for (int d = 0; d < 64; ++d) s = fmaf(os[g][d], wl[i][d], s);
        Mtb[(size_t)(i0 + i) * HDIM + h * 64 + g] = f2bf(s);
    }
}

// ---------------------------------------------------------------------------
// Stage 5: out_f32[M][256] = swb_bf16[M][512] @ Mtb^T + bout  (128x128 tile,
// grid (512,2) — the measured-best round-15 configuration)
// ---------------------------------------------------------------------------
__global__ __launch_bounds__(256)
void gemm_out_kernel(const ushort* __restrict__ A, const ushort* __restrict__ B,
                     const float* __restrict__ bias, float* __restrict__ C) {
    __shared__ __align__(16) ushort Al[128][64];
    __shared__ __align__(16) ushort Bl[128][64];
    const int m0 = blockIdx.x * 128, n0 = blockIdx.y * 128;
    const int t = threadIdx.x, l = t & 63, w = t >> 6;
    const int wr = w >> 1, wc = w & 1;
    const int lr = l & 15, lq = l >> 4;

    f32x4 acc[4][4];
    #pragma unroll
    for (int mi = 0; mi < 4; ++mi)
        #pragma unroll
        for (int ni = 0; ni < 4; ++ni) acc[mi][ni] = (f32x4){0.f, 0.f, 0.f, 0.f};

    for (int ks = 0; ks < 8; ++ks) {          // K-step of 64 (K=512)
        __syncthreads();
        #pragma unroll
        for (int i = 0; i < 4; ++i) {
            int idx = i * 256 + t;
            int row = idx >> 3, g = idx & 7;
            ushort8 av = *(const ushort8*)&A[(size_t)(m0 + row) * 512 + ks * 64 + g * 8];
            *(ushort8*)&Al[row][(g ^ (row & 7)) * 8] = av;
            ushort8 bv = *(const ushort8*)&B[(size_t)(n0 + row) * 512 + ks * 64 + g * 8];
            *(ushort8*)&Bl[row][(g ^ (row & 7)) * 8] = bv;
        }
        __syncthreads();
        #pragma unroll
        for (int kf = 0; kf < 2; ++kf) {
            short8 af[4], bfr[4];
            #pragma unroll
            for (int mi = 0; mi < 4; ++mi) {
                int row = wr * 64 + mi * 16 + lr, g = kf * 4 + lq;
                af[mi] = *(const short8*)&Al[row][(g ^ (row & 7)) * 8];
            }
            #pragma unroll
            for (int ni = 0; ni < 4; ++ni) {
                int row = wc * 64 + ni * 16 + lr, g = kf * 4 + lq;
                bfr[ni] = *(const short8*)&Bl[row][(g ^ (row & 7)) * 8];
            }
            #pragma unroll
            for (int mi = 0; mi < 4; ++mi)
                #pragma unroll
                for (int ni = 0; ni < 4; ++ni)
                    acc[mi][ni] = __builtin_amdgcn_mfma_f32_16x16x32_bf16(
                        af[mi], bfr[ni], acc[mi][ni], 0, 0, 0);
        }
    }
    #pragma unroll
    for (int ni = 0; ni < 4; ++ni) {
        int col = n0 + wc * 64 + ni * 16 + lr;
        float bb = bias[col];
        #pragma unroll
        for (int mi = 0; mi < 4; ++mi)
            #pragma unroll
            for (int j = 0; j < 4; ++j) {
                int row = m0 + wr * 64 + mi * 16 + lq * 4 + j;
                C[(size_t)row * 256 + col] = acc[mi][ni][j] + bb;
            }
    }
}

// ---------------------------------------------------------------------------
extern "C" void kernel_launch(void* const* d_in, const int* in_sizes, int n_in,
                              void* d_out, int out_size, void* d_ws, size_t ws_size,
                              hipStream_t stream) {
    const float* x    = (const float*)d_in[0];
    const float* Wx   = (const float*)d_in[1];
    const float* bx   = (const float*)d_in[2];
    const float* Wt1  = (const float*)d_in[3];
    const float* bt1  = (const float*)d_in[4];
    const float* Wt2  = (const float*)d_in[5];
    const float* bt2  = (const float*)d_in[6];
    const float* biasp= (const float*)d_in[7];
    const float* Ws   = (const float*)d_in[8];
    const float* bs   = (const float*)d_in[9];
    const float* Wq   = (const float*)d_in[10];
    const float* Wk   = (const float*)d_in[11];
    const float* Wv   = (const float*)d_in[12];
    const float* Wout = (const float*)d_in[13];
    const float* bout = (const float*)d_in[14];
    const float* u    = (const float*)d_in[15];
    float* out = (float*)d_out;

    float*  stp    = (float*)d_ws;                           // 8*64*4096 f32 = 8.4 MB
    float*  normp  = stp    + (size_t)NH * 64 * 4096;        // 8*64*64
    float*  st_red = normp  + (size_t)NH * 64 * 64;          // 8*4096
    float*  nrm    = st_red + (size_t)NH * 4096;             // 8*64
    float*  osl    = nrm    + (size_t)NH * 64;               // 8*4096
    ushort* wb     = (ushort*)(osl + (size_t)NH * 4096);     // 128*64 bf16
    ushort* Wxb    = wb  + (size_t)128 * 64;                 // 512*256 bf16
    ushort* Mtb    = Wxb + (size_t)HDIM * DIMX;              // 256*512 bf16
    ushort* xb     = Mtb + (size_t)DIMX * HDIM;              // 65536*256 bf16
    ushort* xmb    = xb  + (size_t)NPTS * DIMX;              // 65536*512 bf16
    ushort* swb    = xmb + (size_t)NPTS * HDIM;              // 65536*512 bf16

    // 0) pre-convert x, Wx and [Ws;Wt1] to bf16
    prep_kernel<<<8260, 256, 0, stream>>>(x, Wx, Ws, Wt1, xb, Wxb, wb);
    // 1+2) fused: xmid GEMM + logits/temp GEMM + gumbel softmax
    xmid_lgt1_kernel<<<dim3(512, 4), 256, 0, stream>>>(xb, Wxb, bx, wb, bs, bt1,
                                                       Wt2, bt2, biasp, u,
                                                       xmb, swb);
    // 3) slice token partials via MFMA (in-block cross-wave reduce)
    gather_mfma_kernel<<<dim3(64, 8), 256, 0, stream>>>(xmb, swb, stp, normp);
    // 4a) reduce partials
    reduce_st_kernel<<<dim3(8, 16), 256, 0, stream>>>(stp, normp, st_red, nrm);
    // 4b) tiny attention
    attn_small_kernel<<<8, 256, 0, stream>>>(st_red, nrm, Wq, Wk, Wv, osl);
    // 4c) fold out_slice into Wout (bf16 output)
    fold_kernel<<<dim3(8, 2), 256, 0, stream>>>(osl, Wout, Mtb);
    // 5) out = sw @ Mtb^T + bout (parallel 128x128, grid 512x2)
    gemm_out_kernel<<<dim3(512, 2), 256, 0, stream>>>(swb, Mtb, bout, out);
}

// Round 21
// 253.545 us; speedup vs baseline: 1.0351x; 1.0229x over previous
//
#include <hip/hip_runtime.h>
#include <math.h>

// Physics_Attention: B=1, N=65536, DIM=256, H=8, D=64, G=64
#define NPTS  65536
#define DIMX  256
#define NH    8
#define HDIM  512   // H*D

typedef __attribute__((ext_vector_type(4))) float f32x4;
typedef __attribute__((ext_vector_type(8))) short short8;
typedef __attribute__((ext_vector_type(8))) unsigned short ushort8;
typedef __attribute__((ext_vector_type(4))) unsigned short us4;

__device__ __forceinline__ ushort f2bf(float f) {   // RNE f32->bf16
    unsigned x = __float_as_uint(f);
    return (ushort)((x + 0x7fffu + ((x >> 16) & 1u)) >> 16);
}
__device__ __forceinline__ float bf2f(ushort u) {
    return __uint_as_float((unsigned)u << 16);
}
// Fast erf (A&S 7.1.26, abs err 1.5e-7) — no branches, HW exp/rcp
__device__ __forceinline__ float erf_fast(float x) {
    float ax = fabsf(x);
    float t  = __builtin_amdgcn_rcpf(1.0f + 0.3275911f * ax);
    float p  = fmaf(fmaf(fmaf(fmaf(1.061405429f, t, -1.453152027f), t,
                   1.421413741f), t, -0.284496736f), t, 0.254829592f) * t;
    float y  = 1.0f - p * __expf(-ax * ax);
    return copysignf(y, x);
}
__device__ __forceinline__ float gelu_fast(float x) {
    return 0.5f * x * (1.0f + erf_fast(x * 0.7071067811865476f));
}

// ---------------------------------------------------------------------------
// Stage 0: pre-convert x (65536x256), Wx (512x256), [Ws;Wt1] (128x64) to bf16.
// ---------------------------------------------------------------------------
__global__ __launch_bounds__(256)
void prep_kernel(const float* __restrict__ x, const float* __restrict__ Wx,
                 const float* __restrict__ Ws, const float* __restrict__ Wt1,
                 ushort* __restrict__ xb, ushort* __restrict__ Wxb,
                 ushort* __restrict__ wb) {
    const int t = threadIdx.x;
    const int b = blockIdx.x;
    if (b < 8192) {
        size_t idx = (size_t)b * 2048 + t * 8;
        float4 a0 = *(const float4*)&x[idx];
        float4 a1 = *(const float4*)&x[idx + 4];
        ushort8 v = { f2bf(a0.x), f2bf(a0.y), f2bf(a0.z), f2bf(a0.w),
                      f2bf(a1.x), f2bf(a1.y), f2bf(a1.z), f2bf(a1.w) };
        *(ushort8*)&xb[idx] = v;
    } else if (b < 8256) {
        int idx = (b - 8192) * 2048 + t * 8;
        float4 a0 = *(const float4*)&Wx[idx];
        float4 a1 = *(const float4*)&Wx[idx + 4];
        ushort8 v = { f2bf(a0.x), f2bf(a0.y), f2bf(a0.z), f2bf(a0.w),
                      f2bf(a1.x), f2bf(a1.y), f2bf(a1.z), f2bf(a1.w) };
        *(ushort8*)&Wxb[idx] = v;
    } else {
        int idx = (b - 8256) * 2048 + t * 8;   // 0..8191
        int row = idx >> 6, col = idx & 63;
        const float* src = (row < 64) ? &Ws[row * 64 + col]
                                      : &Wt1[(row - 64) * 64 + col];
        float4 a0 = *(const float4*)src;
        float4 a1 = *(const float4*)(src + 4);
        ushort8 v = { f2bf(a0.x), f2bf(a0.y), f2bf(a0.z), f2bf(a0.w),
                      f2bf(a1.x), f2bf(a1.y), f2bf(a1.z), f2bf(a1.w) };
        *(ushort8*)&wb[idx] = v;
    }
}

// ---------------------------------------------------------------------------
// Stage 1+2 FUSED; phase-1 K-loop now LDS-double-buffered (issue-early /
// write-late, T14): occupancy is REGISTER-limited to 2 blocks/CU, so 64KB
// LDS costs nothing (160/64=2 also), and the restructure removes one barrier
// per K-step. Prefetch regs (+32 VGPR in flight) keep total <=224 -> still
// 2 waves/SIMD (no r13-style occupancy cliff).
// ---------------------------------------------------------------------------
__global__ __launch_bounds__(256)
void xmid_lgt1_kernel(const ushort* __restrict__ A, const ushort* __restrict__ B,
                      const float* __restrict__ bias,
                      const ushort* __restrict__ wb,
                      const float* __restrict__ bs,  const float* __restrict__ bt1,
                      const float* __restrict__ Wt2, const float* __restrict__ bt2,
                      const float* __restrict__ biasp,
                      const float* __restrict__ u,
                      ushort* __restrict__ xmb, ushort* __restrict__ swb) {
    // dbuf halves: [0,1]=A/B even K-steps, [2,3]=A/B odd; Xl reuses [0,1]
    __shared__ __align__(16) ushort pool[4][128][64];
    const int hp = blockIdx.y;                 // head pair 0..3
    const int m0 = blockIdx.x * 128, n0 = hp * 128;
    const int t = threadIdx.x, l = t & 63, w = t >> 6;
    const int wr = w >> 1, wc = w & 1;
    const int lr = l & 15, lq = l >> 4;
    const float LOG2E = 1.4426950408889634f;
    const float LN2   = 0.6931471805599453f;
    const float SH2   = 36.0673760222f;        // 25*log2e

    // ---------------- phase 1: xmid GEMM (K=256), double-buffered ----------
    f32x4 acc[4][4];
    #pragma unroll
    for (int mi = 0; mi < 4; ++mi)
        #pragma unroll
        for (int ni = 0; ni < 4; ++ni) acc[mi][ni] = (f32x4){0.f, 0.f, 0.f, 0.f};

    // prologue: K-step 0 -> regs -> half 0
    {
        ushort8 pav[4], pbv[4];
        #pragma unroll
        for (int i = 0; i < 4; ++i) {
            int idx = i * 256 + t;
            int row = idx >> 3, g = idx & 7;
            pav[i] = *(const ushort8*)&A[(size_t)(m0 + row) * 256 + g * 8];
            pbv[i] = *(const ushort8*)&B[(size_t)(n0 + row) * 256 + g * 8];
        }
        #pragma unroll
        for (int i = 0; i < 4; ++i) {
            int idx = i * 256 + t;
            int row = idx >> 3, g = idx & 7;
            *(ushort8*)&pool[0][row][(g ^ (row & 7)) * 8] = pav[i];
            *(ushort8*)&pool[1][row][(g ^ (row & 7)) * 8] = pbv[i];
        }
    }
    __syncthreads();

    #pragma unroll
    for (int ks = 0; ks < 4; ++ks) {
        const int cur = ks & 1;
        // issue next K-step's global loads (latency hides under MFMA below)
        ushort8 nav[4], nbv[4];
        if (ks < 3) {
            #pragma unroll
            for (int i = 0; i < 4; ++i) {
                int idx = i * 256 + t;
                int row = idx >> 3, g = idx & 7;
                nav[i] = *(const ushort8*)&A[(size_t)(m0 + row) * 256 + (ks + 1) * 64 + g * 8];
                nbv[i] = *(const ushort8*)&B[(size_t)(n0 + row) * 256 + (ks + 1) * 64 + g * 8];
            }
        }
        // MFMA on current half
        #pragma unroll
        for (int kf = 0; kf < 2; ++kf) {
            short8 af[4], bfr[4];
            #pragma unroll
            for (int mi = 0; mi < 4; ++mi) {
                int row = wr * 64 + mi * 16 + lr, g = kf * 4 + lq;
                af[mi] = *(const short8*)&pool[cur * 2][row][(g ^ (row & 7)) * 8];
            }
            #pragma unroll
            for (int ni = 0; ni < 4; ++ni) {
                int row = wc * 64 + ni * 16 + lr, g = kf * 4 + lq;
                bfr[ni] = *(const short8*)&pool[cur * 2 + 1][row][(g ^ (row & 7)) * 8];
            }
            #pragma unroll
            for (int mi = 0; mi < 4; ++mi)
                #pragma unroll
                for (int ni = 0; ni < 4; ++ni)
                    acc[mi][ni] = __builtin_amdgcn_mfma_f32_16x16x32_bf16(
                        af[mi], bfr[ni], acc[mi][ni], 0, 0, 0);
        }
        // write next tile into the other half; one barrier per K-step
        if (ks < 3) {
            #pragma unroll
            for (int i = 0; i < 4; ++i) {
                int idx = i * 256 + t;
                int row = idx >> 3, g = idx & 7;
                *(ushort8*)&pool[(cur ^ 1) * 2][row][(g ^ (row & 7)) * 8] = nav[i];
                *(ushort8*)&pool[(cur ^ 1) * 2 + 1][row][(g ^ (row & 7)) * 8] = nbv[i];
            }
        }
        __syncthreads();
    }

    // ---------------- xmid tile -> LDS (Xl) + global xmb ----------------
    // Xl reuses pool[0..1] (32KB, contiguous within the single pool array).
    // Last MFMA (ks=3) read half 1; half 0's last reads finished at ks=2,
    // before the ks=2 barrier -> safe to overwrite after the final barrier.
    ushort (* __restrict__ Xl)[128] = (ushort (*)[128])(&pool[0][0][0]);
    #pragma unroll
    for (int ni = 0; ni < 4; ++ni) {
        int colL = wc * 64 + ni * 16 + lr;      // local col 0..127
        float bb = bias[n0 + colL];
        int gg = colL >> 3, c7 = colL & 7;
        #pragma unroll
        for (int mi = 0; mi < 4; ++mi)
            #pragma unroll
            for (int j = 0; j < 4; ++j) {
                int row = wr * 64 + mi * 16 + lq * 4 + j;
                Xl[row][(gg ^ (row & 7)) * 8 + c7] = f2bf(acc[mi][ni][j] + bb);
            }
    }
    __syncthreads();
    // vectorized copy-out to xmb (coalesced 16B stores)
    #pragma unroll
    for (int i = 0; i < 8; ++i) {
        int e = i * 256 + t;                    // 0..2047
        int row = e >> 4, gg = e & 15;
        ushort8 v = *(const ushort8*)&Xl[row][(gg ^ (row & 7)) * 8];
        *(ushort8*)&xmb[(size_t)(m0 + row) * 512 + n0 + gg * 8] = v;
    }

    // ---------------- phase 2: lgt1 per head ----------------
    const float bt2v = bt2[0];
    float bsr[4], bt1r[4], wt2r[4];
    #pragma unroll
    for (int ni = 0; ni < 4; ++ni) {
        bsr[ni]  = bs [ni * 16 + lr];
        bt1r[ni] = bt1[ni * 16 + lr];
        wt2r[ni] = Wt2[ni * 16 + lr];
    }

    #pragma unroll
    for (int hh = 0; hh < 2; ++hh) {
        const int h = hp * 2 + hh;
        const float biasph = biasp[h];

        f32x4 acc2[2][8];
        #pragma unroll
        for (int mi = 0; mi < 2; ++mi)
            #pragma unroll
            for (int ni = 0; ni < 8; ++ni) acc2[mi][ni] = (f32x4){0.f, 0.f, 0.f, 0.f};

        #pragma unroll
        for (int kf = 0; kf < 2; ++kf) {
            const int g = kf * 4 + lq;
            short8 af[2], bfr[8];
            #pragma unroll
            for (int mi = 0; mi < 2; ++mi) {
                int row = w * 32 + mi * 16 + lr;
                int gg = hh * 8 + g;
                af[mi] = *(const short8*)&Xl[row][(gg ^ (row & 7)) * 8];
            }
            #pragma unroll
            for (int ni = 0; ni < 8; ++ni)      // direct from global wb (L2-hot)
                bfr[ni] = *(const short8*)&wb[(size_t)(ni * 16 + lr) * 64 + g * 8];
            #pragma unroll
            for (int mi = 0; mi < 2; ++mi)
                #pragma unroll
                for (int ni = 0; ni < 8; ++ni)
                    acc2[mi][ni] = __builtin_amdgcn_mfma_f32_16x16x32_bf16(
                        af[mi], bfr[ni], acc2[mi][ni], 0, 0, 0);
        }

        #pragma unroll
        for (int mi = 0; mi < 2; ++mi) {
            // just-in-time u loads (partially hidden under the gelu chains)
            float uu[4][4];
            #pragma unroll
            for (int jj = 0; jj < 4; ++jj) {
                const int n = m0 + w * 32 + mi * 16 + lq * 4 + jj;
                const float* up = &u[((size_t)h * NPTS + n) * 64 + lr];
                #pragma unroll
                for (int ni = 0; ni < 4; ++ni) uu[jj][ni] = up[ni * 16];
            }
            // temp-MLP (t1 cols = ni 4..7)
            float ts[4];
            #pragma unroll
            for (int jj = 0; jj < 4; ++jj) {
                float s = 0.f;
                #pragma unroll
                for (int ni = 0; ni < 4; ++ni)
                    s += gelu_fast(acc2[mi][ni + 4][jj] + bt1r[ni]) * wt2r[ni];
                ts[jj] = s;
            }
            #pragma unroll
            for (int off = 1; off <= 8; off <<= 1) {
                #pragma unroll
                for (int jj = 0; jj < 4; ++jj) ts[jj] += __shfl_xor(ts[jj], off);
            }
            float invt[4], invt2[4];
            #pragma unroll
            for (int jj = 0; jj < 4; ++jj) {
                float tmp = gelu_fast(ts[jj] + bt2v) + biasph;
                tmp = fmaxf(tmp, 0.01f);
                invt[jj]  = __builtin_amdgcn_rcpf(tmp);
                invt2[jj] = invt[jj] * LOG2E;
            }
            float sv[4][4], ps[4] = {0.f, 0.f, 0.f, 0.f};
            #pragma unroll
            for (int jj = 0; jj < 4; ++jj) {
                #pragma unroll
                for (int ni = 0; ni < 4; ++ni) {
                    float L1 = __log2f(uu[jj][ni] + 1e-8f);
                    float inner = fmaf(-LN2, L1, 1e-8f);
                    float L2v = __log2f(inner);
                    float base = fmaf(acc2[mi][ni][jj] + bsr[ni], invt2[jj], -SH2);
                    sv[jj][ni] = __builtin_amdgcn_exp2f(fmaf(-invt[jj], L2v, base));
                    ps[jj] += sv[jj][ni];
                }
            }
            #pragma unroll
            for (int off = 1; off <= 8; off <<= 1) {
                #pragma unroll
                for (int jj = 0; jj < 4; ++jj) ps[jj] += __shfl_xor(ps[jj], off);
            }
            #pragma unroll
            for (int jj = 0; jj < 4; ++jj) {
                const int n = m0 + w * 32 + mi * 16 + lq * 4 + jj;
                const float inv = __builtin_amdgcn_rcpf(ps[jj]);
                ushort* sp = &swb[(size_t)n * 512 + h * 64 + lr];
                #pragma unroll
                for (int ni = 0; ni < 4; ++ni)
                    sp[ni * 16] = f2bf(sv[jj][ni] * inv);
            }
        }
    }
}

// ---------------------------------------------------------------------------
// Stage 3 (MFMA): per (h, 1024-pt chunk): C[g][c] = sum_n sw[n][g]*x[n][c]
// Cross-wave reduce via LDS (single contiguous `tile` array).
// ---------------------------------------------------------------------------
__global__ __launch_bounds__(256)
void gather_mfma_kernel(const ushort* __restrict__ xmb, const ushort* __restrict__ swb,
                        float* __restrict__ stp, float* __restrict__ normp) {
    __shared__ __align__(16) ushort tile[2][64][128];   // [0]=swT, [1]=xT
    ushort (* __restrict__ swT)[128] = tile[0];
    ushort (* __restrict__ xT )[128] = tile[1];
    const int h  = blockIdx.y;
    const int n0 = blockIdx.x * 1024;
    const int t  = threadIdx.x, l = t & 63, w = t >> 6;
    const int lr = l & 15, lq = l >> 4;
    const int gb = t & 7;
    const int ng = t >> 3;

    f32x4 acc[4][4];
    #pragma unroll
    for (int gi = 0; gi < 4; ++gi)
        #pragma unroll
        for (int ci = 0; ci < 4; ++ci) acc[gi][ci] = (f32x4){0.f, 0.f, 0.f, 0.f};
    float nrm8[8];
    #pragma unroll
    for (int j = 0; j < 8; ++j) nrm8[j] = 0.f;

    for (int r = 0; r < 8; ++r) {
        const int nt = n0 + r * 128;
        ushort8 sv[4], xv[4];
        #pragma unroll
        for (int i = 0; i < 4; ++i) {
            int n = nt + ng * 4 + i;
            sv[i] = *(const ushort8*)&swb[(size_t)n * 512 + h * 64 + gb * 8];
            xv[i] = *(const ushort8*)&xmb[(size_t)n * 512 + h * 64 + gb * 8];
        }
        __syncthreads();
        #pragma unroll
        for (int j = 0; j < 8; ++j) {
            int g   = gb * 8 + j;
            int swz = (ng >> 1) ^ (g & 7) ^ ((g >> 3) & 7);
            int off = swz * 8 + (ng & 1) * 4;
            us4 s4 = { sv[0][j], sv[1][j], sv[2][j], sv[3][j] };
            us4 x4 = { xv[0][j], xv[1][j], xv[2][j], xv[3][j] };
            *(us4*)&swT[g][off] = s4;
            *(us4*)&xT [g][off] = x4;
            nrm8[j] += (bf2f(sv[0][j]) + bf2f(sv[1][j]))
                     + (bf2f(sv[2][j]) + bf2f(sv[3][j]));
        }
        __syncthreads();
        short8 af[4], bfr[4];
        #pragma unroll
        for (int gi = 0; gi < 4; ++gi) {
            int g   = gi * 16 + lr;
            int swz = (w * 4 + lq) ^ (g & 7) ^ ((g >> 3) & 7);
            af[gi]  = *(const short8*)&swT[g][swz * 8];
            bfr[gi] = *(const short8*)&xT [g][swz * 8];
        }
        #pragma unroll
        for (int gi = 0; gi < 4; ++gi)
            #pragma unroll
            for (int ci = 0; ci < 4; ++ci)
                acc[gi][ci] = __builtin_amdgcn_mfma_f32_16x16x32_bf16(
                    af[gi], bfr[ci], acc[gi][ci], 0, 0, 0);
    }

    // cross-wave reduce via LDS: sred[4][32][64] f32 = 32KB (contiguous)
    float* sred = (float*)tile;
    const size_t stbase = ((size_t)h * 64 + blockIdx.x) * 4096;
    #pragma unroll
    for (int half = 0; half < 2; ++half) {
        __syncthreads();
        #pragma unroll
        for (int gg = 0; gg < 2; ++gg) {
            int gi = half * 2 + gg;
            #pragma unroll
            for (int ci = 0; ci < 4; ++ci)
                #pragma unroll
                for (int j = 0; j < 4; ++j)
                    sred[(w * 32 + gg * 16 + lq * 4 + j) * 64 + ci * 16 + lr]
                        = acc[gi][ci][j];
        }
        __syncthreads();
        #pragma unroll
        for (int i = 0; i < 8; ++i) {
            int e = i * 256 + t;            // 0..2047
            float s = (sred[e] + sred[2048 + e]) + (sred[4096 + e] + sred[6144 + e]);
            stp[stbase + half * 2048 + e] = s;
        }
    }

    __syncthreads();
    float* narr = (float*)tile;
    #pragma unroll
    for (int j = 0; j < 8; ++j) narr[ng * 64 + gb * 8 + j] = nrm8[j];
    __syncthreads();
    if (t < 64) {
        float s = 0.f;
        #pragma unroll 8
        for (int k = 0; k < 32; ++k) s += narr[k * 64 + t];
        normp[((size_t)h * 64 + blockIdx.x) * 64 + t] = s;
    }
}

// ---------------------------------------------------------------------------
// Stage 4a: reduce chunk partials -> st_red, nrm
// ---------------------------------------------------------------------------
__global__ __launch_bounds__(256)
void reduce_st_kernel(const float* __restrict__ stp, const float* __restrict__ normp,
                      float* __restrict__ st_red, float* __restrict__ nrm) {
    const int h = blockIdx.x;
    const int e = blockIdx.y * 256 + threadIdx.x;
    float s = 0.f;
    #pragma unroll 8
    for (int ch = 0; ch < 64; ++ch)
        s += stp[((size_t)h * 64 + ch) * 4096 + e];
    st_red[(size_t)h * 4096 + e] = s;
    if (blockIdx.y == 0 && threadIdx.x < 64) {
        float ns = 0.f;
        #pragma unroll 8
        for (int ch = 0; ch < 64; ++ch)
            ns += normp[((size_t)h * 64 + ch) * 64 + threadIdx.x];
        nrm[h * 64 + threadIdx.x] = ns + 1e-5f;
    }
}

// ---------------------------------------------------------------------------
// Stage 4b: per head: normalize tokens, qkv, 64x64 attention -> osl
// ---------------------------------------------------------------------------
__global__ __launch_bounds__(256)
void attn_small_kernel(const float* __restrict__ st_red, const float* __restrict__ nrm,
                       const float* __restrict__ Wq, const float* __restrict__ Wk,
                       const float* __restrict__ Wv, float* __restrict__ osl) {
    __shared__ float st[64][68];
    __shared__ float ql[64][68];
    __shared__ float kl[64][68];
    __shared__ float vl[64][68];
    __shared__ float sc[64][68];
    __shared__ float nl[64];
    const int h = blockIdx.x;
    const int t = threadIdx.x;

    if (t < 64) nl[t] = nrm[h * 64 + t];
    __syncthreads();
    for (int e = t; e < 4096; e += 256)
        st[e>>6][e&63] = st_red[(size_t)h * 4096 + e] / nl[e>>6];
    __syncthreads();
    for (int e = t; e < 4096; e += 256) {
        int g = e >> 6, dd = e & 63;
        float aq = 0.f, ak = 0.f, av = 0.f;
        for (int cc = 0; cc < 64; ++cc) {
            float sv = st[g][cc];
            aq = fmaf(sv, Wq[dd*64 + cc], aq);
            ak = fmaf(sv, Wk[dd*64 + cc], ak);
            av = fmaf(sv, Wv[dd*64 + cc], av);
        }
        ql[g][dd] = aq; kl[g][dd] = ak; vl[g][dd] = av;
    }
    __syncthreads();
    for (int e = t; e < 4096; e += 256) {
        int g = e >> 6, gp = e & 63;
        float s = 0.f;
        for (int dd = 0; dd < 64; ++dd) s = fmaf(ql[g][dd], kl[gp][dd], s);
        sc[g][gp] = s * 0.125f;
    }
    __syncthreads();
    if (t < 64) {
        float m = -1e30f;
        for (int j = 0; j < 64; ++j) m = fmaxf(m, sc[t][j]);
        float ssum = 0.f;
        for (int j = 0; j < 64; ++j) { float p = expf(sc[t][j] - m); sc[t][j] = p; ssum += p; }
        float inv = 1.f / ssum;
        for (int j = 0; j < 64; ++j) sc[t][j] *= inv;
    }
    __syncthreads();
    for (int e = t; e < 4096; e += 256) {
        int g = e >> 6, dd = e & 63;
        float s = 0.f;
        for (int gp = 0; gp < 64; ++gp) s = fmaf(sc[g][gp], vl[gp][dd], s);
        osl[(size_t)h * 4096 + e] = s;
    }
}

// ---------------------------------------------------------------------------
// Stage 4c: fold out_slice into Wout: Mtb[i][h*64+g] (bf16 output)
// ---------------------------------------------------------------------------
__global__ __launch_bounds__(256)
void fold_kernel(const float* __restrict__ osl, const float* __restrict__ Wout,
                 ushort* __restrict__ Mtb) {
    __shared__ float os[64][65];
    __shared__ float wl[128][65];
    const int h  = blockIdx.x;
    const int i0 = blockIdx.y * 128;
    const int t  = threadIdx.x;
    for (int e = t; e < 4096; e += 256) os[e>>6][e&63] = osl[(size_t)h * 4096 + e];
    for (int e = t; e < 8192; e += 256) {
        int i = e >> 6, d = e & 63;
        wl[i][d] = Wout[(size_t)(i0 + i) * HDIM + h * 64 + d];
    }
    __syncthreads();
    const int g = t & 63, iq = t >> 6;
    #pragma unroll 4
    for (int k = 0; k < 32; ++k) {
        int i = iq * 32 + k;
        float s = 0.f;
        #pragma unroll
        for (int d = 0; d < 64; ++d) s = fmaf(os[g][d], wl[i][d], s);
        Mtb[(size_t)(i0 + i) * HDIM + h * 64 + g] = f2bf(s);
    }
}

// ---------------------------------------------------------------------------
// Stage 5: out_f32[M][256] = swb_bf16[M][512] @ Mtb^T + bout  (128x128 tile,
// grid (512,2) — measured-best configuration)
// ---------------------------------------------------------------------------
__global__ __launch_bounds__(256)
void gemm_out_kernel(const ushort* __restrict__ A, const ushort* __restrict__ B,
                     const float* __restrict__ bias, float* __restrict__ C) {
    __shared__ __align__(16) ushort Al[128][64];
    __shared__ __align__(16) ushort Bl[128][64];
    const int m0 = blockIdx.x * 128, n0 = blockIdx.y * 128;
    const int t = threadIdx.x, l = t & 63, w = t >> 6;
    const int wr = w >> 1, wc = w & 1;
    const int lr = l & 15, lq = l >> 4;

    f32x4 acc[4][4];
    #pragma unroll
    for (int mi = 0; mi < 4; ++mi)
        #pragma unroll
        for (int ni = 0; ni < 4; ++ni) acc[mi][ni] = (f32x4){0.f, 0.f, 0.f, 0.f};

    for (int ks = 0; ks < 8; ++ks) {          // K-step of 64 (K=512)
        __syncthreads();
        #pragma unroll
        for (int i = 0; i < 4; ++i) {
            int idx = i * 256 + t;
            int row = idx >> 3, g = idx & 7;
            ushort8 av = *(const ushort8*)&A[(size_t)(m0 + row) * 512 + ks * 64 + g * 8];
            *(ushort8*)&Al[row][(g ^ (row & 7)) * 8] = av;
            ushort8 bv = *(const ushort8*)&B[(size_t)(n0 + row) * 512 + ks * 64 + g * 8];
            *(ushort8*)&Bl[row][(g ^ (row & 7)) * 8] = bv;
        }
        __syncthreads();
        #pragma unroll
        for (int kf = 0; kf < 2; ++kf) {
            short8 af[4], bfr[4];
            #pragma unroll
            for (int mi = 0; mi < 4; ++mi) {
                int row = wr * 64 + mi * 16 + lr, g = kf * 4 + lq;
                af[mi] = *(const short8*)&Al[row][(g ^ (row & 7)) * 8];
            }
            #pragma unroll
            for (int ni = 0; ni < 4; ++ni) {
                int row = wc * 64 + ni * 16 + lr, g = kf * 4 + lq;
                bfr[ni] = *(const short8*)&Bl[row][(g ^ (row & 7)) * 8];
            }
            #pragma unroll
            for (int mi = 0; mi < 4; ++mi)
                #pragma unroll
                for (int ni = 0; ni < 4; ++ni)
                    acc[mi][ni] = __builtin_amdgcn_mfma_f32_16x16x32_bf16(
                        af[mi], bfr[ni], acc[mi][ni], 0, 0, 0);
        }
    }
    #pragma unroll
    for (int ni = 0; ni < 4; ++ni) {
        int col = n0 + wc * 64 + ni * 16 + lr;
        float bb = bias[col];
        #pragma unroll
        for (int mi = 0; mi < 4; ++mi)
            #pragma unroll
            for (int j = 0; j < 4; ++j) {
                int row = m0 + wr * 64 + mi * 16 + lq * 4 + j;
                C[(size_t)row * 256 + col] = acc[mi][ni][j] + bb;
            }
    }
}

// ---------------------------------------------------------------------------
extern "C" void kernel_launch(void* const* d_in, const int* in_sizes, int n_in,
                              void* d_out, int out_size, void* d_ws, size_t ws_size,
                              hipStream_t stream) {
    const float* x    = (const float*)d_in[0];
    const float* Wx   = (const float*)d_in[1];
    const float* bx   = (const float*)d_in[2];
    const float* Wt1  = (const float*)d_in[3];
    const float* bt1  = (const float*)d_in[4];
    const float* Wt2  = (const float*)d_in[5];
    const float* bt2  = (const float*)d_in[6];
    const float* biasp= (const float*)d_in[7];
    const float* Ws   = (const float*)d_in[8];
    const float* bs   = (const float*)d_in[9];
    const float* Wq   = (const float*)d_in[10];
    const float* Wk   = (const float*)d_in[11];
    const float* Wv   = (const float*)d_in[12];
    const float* Wout = (const float*)d_in[13];
    const float* bout = (const float*)d_in[14];
    const float* u    = (const float*)d_in[15];
    float* out = (float*)d_out;

    float*  stp    = (float*)d_ws;                           // 8*64*4096 f32 = 8.4 MB
    float*  normp  = stp    + (size_t)NH * 64 * 4096;        // 8*64*64
    float*  st_red = normp  + (size_t)NH * 64 * 64;          // 8*4096
    float*  nrm    = st_red + (size_t)NH * 4096;             // 8*64
    float*  osl    = nrm    + (size_t)NH * 64;               // 8*4096
    ushort* wb     = (ushort*)(osl + (size_t)NH * 4096);     // 128*64 bf16
    ushort* Wxb    = wb  + (size_t)128 * 64;                 // 512*256 bf16
    ushort* Mtb    = Wxb + (size_t)HDIM * DIMX;              // 256*512 bf16
    ushort* xb     = Mtb + (size_t)DIMX * HDIM;              // 65536*256 bf16
    ushort* xmb    = xb  + (size_t)NPTS * DIMX;              // 65536*512 bf16
    ushort* swb    = xmb + (size_t)NPTS * HDIM;              // 65536*512 bf16

    // 0) pre-convert x, Wx and [Ws;Wt1] to bf16
    prep_kernel<<<8260, 256, 0, stream>>>(x, Wx, Ws, Wt1, xb, Wxb, wb);
    // 1+2) fused: xmid GEMM (double-buffered) + lgt1 + gumbel softmax
    xmid_lgt1_kernel<<<dim3(512, 4), 256, 0, stream>>>(xb, Wxb, bx, wb, bs, bt1,
                                                       Wt2, bt2, biasp, u,
                                                       xmb, swb);
    // 3) slice token partials via MFMA (in-block cross-wave reduce)
    gather_mfma_kernel<<<dim3(64, 8), 256, 0, stream>>>(xmb, swb, stp, normp);
    // 4a) reduce partials
    reduce_st_kernel<<<dim3(8, 16), 256, 0, stream>>>(stp, normp, st_red, nrm);
    // 4b) tiny attention
    attn_small_kernel<<<8, 256, 0, stream>>>(st_red, nrm, Wq, Wk, Wv, osl);
    // 4c) fold out_slice into Wout (bf16 output)
    fold_kernel<<<dim3(8, 2), 256, 0, stream>>>(osl, Wout, Mtb);
    // 5) out = sw @ Mtb^T + bout (parallel 128x128, grid 512x2)
    gemm_out_kernel<<<dim3(512, 2), 256, 0, stream>>>(swb, Mtb, bout, out);
}